// Round 2
// baseline (265.807 us; speedup 1.0000x reference)
//
#include <hip/hip_runtime.h>

// Problem constants
#define MROWS 512            // B*S
#define VDIM  50257          // vocab
#define KP    50272          // VDIM padded to multiple of 32 (= 32*1571)
#define NDIM  1024           // D
#define NSTEPS (KP / 32)     // 1571 K-steps of 32
#define KSPLIT 32
#define SC    50             // ceil(NSTEPS / KSPLIT)
#define PRED_OFF 524288      // 512*1024
#define PP_OFF   524800      // + 512
#define NCONVW 12576         // 786*16 transpose tiles

typedef unsigned short u16;
typedef unsigned int   u32;
typedef __bf16 bf16x8 __attribute__((ext_vector_type(8)));
typedef float  f32x4  __attribute__((ext_vector_type(4)));

__device__ __forceinline__ u16 f2bf(float f) {
  u32 u = __float_as_uint(f);
  u32 r = (u + 0x7fffu + ((u >> 16) & 1u)) >> 16;  // RNE
  return (u16)r;
}

__device__ __forceinline__ void gl_lds16(const u16* g, u16* l) {
  __builtin_amdgcn_global_load_lds(
      (const __attribute__((address_space(1))) u32*)(g),
      (__attribute__((address_space(3))) u32*)(l), 16, 0, 0);
}

// ---------------------------------------------------------------------------
// Fused kernel: blocks [0, NCONVW) transpose+convert W -> BT bf16;
// blocks [NCONVW, NCONVW+512) do per-row copy+argmax+bf16 of P, zero emb.
// Fusion lets the two memory streams co-reside (prep alone = 2 blocks/CU).
// ---------------------------------------------------------------------------
__global__ __launch_bounds__(256) void prep_fused(const float* __restrict__ P,
                                                  const float* __restrict__ W,
                                                  float* __restrict__ out,
                                                  u16* __restrict__ A,
                                                  u16* __restrict__ BT)
{
  const int tid = threadIdx.x;
  if (blockIdx.x < NCONVW) {
    // ---- convw: 64x64 tile transpose via LDS ----
    __shared__ u16 t[64][65];
    const int bx  = blockIdx.x;
    const int dt  = bx & 15;
    const int vt  = bx >> 4;
    const int v0  = vt << 6;
    const int d0  = dt << 6;
    const int c16 = tid & 15;
    const int r16 = tid >> 4;
#pragma unroll
    for (int p = 0; p < 4; ++p) {
      const int v  = v0 + p * 16 + r16;
      const int vl = p * 16 + r16;
      float4 w = make_float4(0.f, 0.f, 0.f, 0.f);
      if (v < VDIM) w = *(const float4*)(W + (size_t)v * NDIM + d0 + c16 * 4);
      t[c16 * 4 + 0][vl] = f2bf(w.x);
      t[c16 * 4 + 1][vl] = f2bf(w.y);
      t[c16 * 4 + 2][vl] = f2bf(w.z);
      t[c16 * 4 + 3][vl] = f2bf(w.w);
    }
    __syncthreads();
#pragma unroll
    for (int p = 0; p < 4; ++p) {
      const int dl = p * 16 + r16;
      const int vl = c16 * 4;
      const int v  = v0 + vl;
      if (v + 3 < KP) {
        ushort4 o;
        o.x = t[dl][vl]; o.y = t[dl][vl + 1]; o.z = t[dl][vl + 2]; o.w = t[dl][vl + 3];
        *(ushort4*)(BT + (size_t)(d0 + dl) * KP + v) = o;
      }
    }
  } else {
    // ---- prep: row copy + argmax + bf16 convert; zero emb row ----
    const int m = blockIdx.x - NCONVW;
    const float* src = P + (size_t)m * VDIM;
    float*       cpy = out + PP_OFF + (size_t)m * VDIM;
    u16*        arow = A + (size_t)m * KP;

    { f32x4 z = {}; *(f32x4*)(out + (size_t)m * NDIM + tid * 4) = z; }

    float bv = -3.4e38f;
    int   bi = 0;
    const int h    = (4 - (m & 3)) & 3;
    const int nvec = (VDIM - h) >> 2;

    if (tid < h) {
      float v = src[tid];
      cpy[tid] = v;
      arow[tid] = f2bf(v);
      if (v > bv) { bv = v; bi = tid; }
    }
    for (int i = tid; i < nvec; i += 256) {
      const int v0i = h + (i << 2);
      f32x4 v = *(const f32x4*)(src + v0i);
      *(f32x4*)(cpy + v0i) = v;
      arow[v0i + 0] = f2bf(v[0]);
      arow[v0i + 1] = f2bf(v[1]);
      arow[v0i + 2] = f2bf(v[2]);
      arow[v0i + 3] = f2bf(v[3]);
      if (v[0] > bv) { bv = v[0]; bi = v0i; }
      if (v[1] > bv) { bv = v[1]; bi = v0i + 1; }
      if (v[2] > bv) { bv = v[2]; bi = v0i + 2; }
      if (v[3] > bv) { bv = v[3]; bi = v0i + 3; }
    }
    const int t0    = h + (nvec << 2);
    const int ntail = VDIM - t0;
    if (tid < ntail) {
      const int v0i = t0 + tid;
      float v = src[v0i];
      cpy[v0i] = v;
      arow[v0i] = f2bf(v);
      if (v > bv) { bv = v; bi = v0i; }
    }
    if (tid < KP - VDIM) arow[VDIM + tid] = 0;

    __shared__ float sv[256];
    __shared__ int   si[256];
    sv[tid] = bv; si[tid] = bi;
    __syncthreads();
    for (int s = 128; s > 0; s >>= 1) {
      if (tid < s) {
        float ov = sv[tid + s]; int oi = si[tid + s];
        if (ov > sv[tid] || (ov == sv[tid] && oi < si[tid])) { sv[tid] = ov; si[tid] = oi; }
      }
      __syncthreads();
    }
    if (tid == 0) out[PRED_OFF + m] = (float)si[0];
  }
}

// ---------------------------------------------------------------------------
// GEMM: bf16 MFMA, 128x128 tile, BK=32, double-buffered LDS (2-phase
// pipeline: stage next || compute current, ONE vmcnt(0)+barrier per step),
// split-K=32 (1024 blocks = 4/CU), atomicAdd f32 epilogue.
// ---------------------------------------------------------------------------
__global__ __launch_bounds__(256) void gemm_kernel(const u16* __restrict__ A,
                                                   const u16* __restrict__ BT,
                                                   float* __restrict__ out)
{
  __shared__ u16 ldsA[2][128 * 32];
  __shared__ u16 ldsB[2][128 * 32];

  const int bx  = blockIdx.x;
  const int kc  = bx >> 5;
  const int mn  = bx & 31;
  const int m0  = (mn & 3) << 7;
  const int n0  = (mn >> 2) << 7;
  const int ks0 = kc * SC;
  const int ks1 = min(NSTEPS, ks0 + SC);
  const int tid  = threadIdx.x;
  const int wid  = tid >> 6;
  const int lane = tid & 63;
  const int wrow = (wid >> 1) << 6;
  const int wcol = (wid & 1) << 6;

  const u16* gA = A  + (size_t)(m0 + wid * 16 + (lane >> 2)) * KP + ((lane & 3) << 3);
  const u16* gB = BT + (size_t)(n0 + wid * 16 + (lane >> 2)) * KP + ((lane & 3) << 3);
  const int ldoff = wid * 512;   // wave-uniform LDS dst (1KB/wave per issue)

  f32x4 acc[4][4] = {};

  const int r  = lane & 15;
  const int hh = lane >> 4;
  const int fragA_off = (wrow + r) * 32 + hh * 8;
  const int fragB_off = (wcol + r) * 32 + hh * 8;

#define STAGE(buf, ks)                                            \
  do {                                                            \
    const int k_ = (ks) << 5;                                     \
    gl_lds16(gA + k_,                ldsA[buf] + ldoff);          \
    gl_lds16(gA + k_ + (size_t)64*KP, ldsA[buf] + ldoff + 2048);  \
    gl_lds16(gB + k_,                ldsB[buf] + ldoff);          \
    gl_lds16(gB + k_ + (size_t)64*KP, ldsB[buf] + ldoff + 2048);  \
  } while (0)

  STAGE(0, ks0);
  asm volatile("s_waitcnt vmcnt(0)" ::: "memory");
  __builtin_amdgcn_s_barrier();

  int cur = 0;
  for (int ks = ks0; ks < ks1; ++ks) {
    if (ks + 1 < ks1) STAGE(cur ^ 1, ks + 1);  // prefetch overlaps compute

    bf16x8 av[4], bv[4];
    const u16* lAr = ldsA[cur] + fragA_off;
    const u16* lBr = ldsB[cur] + fragB_off;
#pragma unroll
    for (int i = 0; i < 4; ++i) av[i] = *(const bf16x8*)(lAr + i * 16 * 32);
#pragma unroll
    for (int j = 0; j < 4; ++j) bv[j] = *(const bf16x8*)(lBr + j * 16 * 32);
#pragma unroll
    for (int i = 0; i < 4; ++i)
#pragma unroll
      for (int j = 0; j < 4; ++j)
        acc[i][j] = __builtin_amdgcn_mfma_f32_16x16x32_bf16(av[i], bv[j], acc[i][j], 0, 0, 0);

    asm volatile("s_waitcnt vmcnt(0)" ::: "memory");  // next buffer landed
    __builtin_amdgcn_s_barrier();                     // + all reads of cur done
    cur ^= 1;
  }
#undef STAGE

  const int col = lane & 15;
  const int r4  = (lane >> 4) << 2;
#pragma unroll
  for (int i = 0; i < 4; ++i)
#pragma unroll
    for (int j = 0; j < 4; ++j)
#pragma unroll
      for (int rr = 0; rr < 4; ++rr) {
        const int mm = m0 + wrow + i * 16 + r4 + rr;
        const int nn = n0 + wcol + j * 16 + col;
        atomicAdd(out + (size_t)mm * NDIM + nn, acc[i][j][rr]);
      }
}

// ---------------------------------------------------------------------------
extern "C" void kernel_launch(void* const* d_in, const int* in_sizes, int n_in,
                              void* d_out, int out_size, void* d_ws, size_t ws_size,
                              hipStream_t stream) {
  const float* P = (const float*)d_in[0];   // [512][50257]
  const float* W = (const float*)d_in[1];   // [50257][1024]
  float* out = (float*)d_out;
  u16* A  = (u16*)d_ws;                     // [512][KP] bf16  (51.5 MB)
  u16* BT = A + (size_t)MROWS * KP;         // [1024][KP] bf16 (103 MB)

  prep_fused<<<NCONVW + MROWS, 256, 0, stream>>>(P, W, out, A, BT);
  gemm_kernel<<<32 * KSPLIT, 256, 0, stream>>>(A, BT, out);
}

// Round 3
// 251.514 us; speedup vs baseline: 1.0568x; 1.0568x over previous
//
#include <hip/hip_runtime.h>

// Problem constants
#define MROWS 512            // B*S
#define VDIM  50257          // vocab
#define KP    50272          // VDIM padded to multiple of 32 (= 32*1571)
#define NDIM  1024           // D
#define NSTEPS 1571          // KP/32
#define KSPLIT 32
#define SC     50            // ceil(NSTEPS / KSPLIT)
#define PRED_OFF 524288      // 512*1024
#define PP_OFF   524800      // + 512
#define NPREP  4096          // 512 rows x 8 chunks
#define CHUNK  6284          // multiple of 4; 8*6284 >= VDIM
#define NCONVW 12576         // 786*16 transpose tiles

typedef unsigned short u16;
typedef unsigned int   u32;
typedef unsigned long long u64;
typedef __bf16 bf16x8 __attribute__((ext_vector_type(8)));
typedef float  f32x4  __attribute__((ext_vector_type(4)));
typedef float  f32x4u __attribute__((ext_vector_type(4), aligned(4)));

__device__ __forceinline__ u16 f2bf(float f) {
  u32 u = __float_as_uint(f);
  u32 r = (u + 0x7fffu + ((u >> 16) & 1u)) >> 16;  // RNE
  return (u16)r;
}

__device__ __forceinline__ void gl_lds16(const u16* g, u16* l) {
  __builtin_amdgcn_global_load_lds(
      (const __attribute__((address_space(1))) u32*)(g),
      (__attribute__((address_space(3))) u32*)(l), 16, 0, 0);
}

// ---------------------------------------------------------------------------
// Fused prep: blocks [0, NPREP) = row-chunk copy/argmax/bf16 of P (8 per row,
// uniform ~63KB each, dispatched first); blocks [NPREP, +NCONVW) = W transpose.
// ---------------------------------------------------------------------------
__global__ __launch_bounds__(256) void prep_fused(const float* __restrict__ P,
                                                  const float* __restrict__ W,
                                                  float* __restrict__ out,
                                                  u16* __restrict__ A,
                                                  u16* __restrict__ BT,
                                                  u64* __restrict__ amax)
{
  const int tid = threadIdx.x;
  if (blockIdx.x < NPREP) {
    // ---- prep chunk: rows split 8 ways ----
    const int m  = blockIdx.x >> 3;
    const int c  = blockIdx.x & 7;
    const int s0 = c * CHUNK;
    const int len = min(VDIM - s0, CHUNK);
    const float* src = P + (size_t)m * VDIM + s0;
    float*       cpy = out + PP_OFF + (size_t)m * VDIM + s0;
    u16*        arow = A + (size_t)m * KP + s0;

    // zero this block's slice of pred_emb row m (128 floats)
    if (tid < 32) { f32x4 z = {}; *(f32x4*)(out + (size_t)m * NDIM + c * 128 + tid * 4) = z; }

    u64 best = 0;  // packed (f32 bits << 32) | (0xFFFF - idx); p>0 so bits>0
    const int nvec = len >> 2;
    for (int i = tid; i < nvec; i += 256) {
      const int v0i = i << 2;
      f32x4u v = *(const f32x4u*)(src + v0i);     // 4B-aligned vector ld
      *(f32x4u*)(cpy + v0i) = v;
      ushort4 o;
      o.x = f2bf(v[0]); o.y = f2bf(v[1]); o.z = f2bf(v[2]); o.w = f2bf(v[3]);
      *(ushort4*)(arow + v0i) = o;                // s0,v0i mult of 4 -> 8B aligned
#pragma unroll
      for (int q = 0; q < 4; ++q) {
        u64 pk = ((u64)__float_as_uint(v[q]) << 32) | (u64)(0xFFFFu - (u32)(s0 + v0i + q));
        best = best > pk ? best : pk;
      }
    }
    if ((len & 3) && tid == 0) {                  // last chunk straggler (1 elem)
      const int v0i = len & ~3;
      float v = src[v0i];
      cpy[v0i] = v;
      arow[v0i] = f2bf(v);
      u64 pk = ((u64)__float_as_uint(v) << 32) | (u64)(0xFFFFu - (u32)(s0 + v0i));
      best = best > pk ? best : pk;
    }
    if (c == 7 && tid < KP - VDIM) arow[(VDIM - s0) + tid] = 0;  // K-pad

    __shared__ u64 sb[256];
    sb[tid] = best;
    __syncthreads();
    for (int s = 128; s > 0; s >>= 1) {
      if (tid < s) { u64 o = sb[tid + s]; if (o > sb[tid]) sb[tid] = o; }
      __syncthreads();
    }
    if (tid == 0) atomicMax(&amax[m], sb[0]);
  } else {
    // ---- convw: 64x64 tile transpose via LDS ----
    __shared__ u16 t[64][65];
    const int bx  = blockIdx.x - NPREP;
    const int dt  = bx & 15;
    const int vt  = bx >> 4;
    const int v0  = vt << 6;
    const int d0  = dt << 6;
    const int c16 = tid & 15;
    const int r16 = tid >> 4;
#pragma unroll
    for (int p = 0; p < 4; ++p) {
      const int v  = v0 + p * 16 + r16;
      const int vl = p * 16 + r16;
      float4 w = make_float4(0.f, 0.f, 0.f, 0.f);
      if (v < VDIM) w = *(const float4*)(W + (size_t)v * NDIM + d0 + c16 * 4);
      t[c16 * 4 + 0][vl] = f2bf(w.x);
      t[c16 * 4 + 1][vl] = f2bf(w.y);
      t[c16 * 4 + 2][vl] = f2bf(w.z);
      t[c16 * 4 + 3][vl] = f2bf(w.w);
    }
    __syncthreads();
#pragma unroll
    for (int p = 0; p < 4; ++p) {
      const int dl = p * 16 + r16;
      const int vl = c16 * 4;
      const int v  = v0 + vl;
      if (v + 3 < KP) {
        ushort4 o;
        o.x = t[dl][vl]; o.y = t[dl][vl + 1]; o.z = t[dl][vl + 2]; o.w = t[dl][vl + 3];
        *(ushort4*)(BT + (size_t)(d0 + dl) * KP + v) = o;
      }
    }
  }
}

// ---------------------------------------------------------------------------
// GEMM: 256x256 tile, 8 waves (2m x 4n, 128x64 each), BK=32, double-buffered
// LDS (64KB) with XOR-swizzled k-blocks (staged via pre-swizzled global src),
// split-K=32 -> 256 blocks = 1/CU, XCD-grouped decode, atomicAdd epilogue.
// ---------------------------------------------------------------------------
__global__ __launch_bounds__(512, 2) void gemm_kernel(const u16* __restrict__ A,
                                                      const u16* __restrict__ BT,
                                                      const u64* __restrict__ amax,
                                                      float* __restrict__ out)
{
  __shared__ u16 ldsA[2][256 * 32];
  __shared__ u16 ldsB[2][256 * 32];

  const int bx  = blockIdx.x;
  // XCD grouping: the 8 blocks of one kc (sharing A/B panels) land on one XCD
  const int kc  = (bx & 7) | ((bx >> 6) << 3);
  const int mn  = (bx >> 3) & 7;
  const int m0  = (mn & 1) << 8;
  const int n0  = (mn >> 1) << 8;
  const int ks0 = kc * SC;
  const int ks1 = min(NSTEPS, ks0 + SC);
  const int tid  = threadIdx.x;
  const int wid  = tid >> 6;
  const int lane = tid & 63;
  const int wr   = wid >> 2;   // 0..1
  const int wc   = wid & 3;    // 0..3

  // finalize predictions (amax written by prep kernel; distinct out region)
  if (bx == 0) {
    u64 p = amax[tid];
    out[PRED_OFF + tid] = (float)(0xFFFF - (int)(p & 0xFFFFu));
  }

  // staging: lane covers (row=lane>>2, kblock=lane&3); source pre-swizzled so
  // LDS slot (row,kb) holds global k-block kb^g(row)  [rule 21: both sides]
  const int srow = lane >> 2;
  const int kb   = lane & 3;
  const int gsw  = (srow & 3) ^ ((srow >> 2) & 3);
  const u16* gA = A  + (size_t)(m0 + wid * 32 + srow) * KP + ((kb ^ gsw) << 3);
  const u16* gB = BT + (size_t)(n0 + wid * 32 + srow) * KP + ((kb ^ gsw) << 3);
  const int ldoff = wid * 1024;   // wave-uniform LDS base (32 rows x 32 elems)

  f32x4 acc[8][4] = {};

  // fragment read: row r, k-half hh, swizzled k-block
  const int r   = lane & 15;
  const int hh  = lane >> 4;
  const int kbr = ((hh ^ ((r & 3) ^ ((r >> 2) & 3))) << 3);

#define STAGE(buf, ks) do {                                      \
    const int k_ = (ks) << 5;                                    \
    gl_lds16(gA + k_,                 ldsA[buf] + ldoff);        \
    gl_lds16(gA + k_ + (size_t)16*KP, ldsA[buf] + ldoff + 512);  \
    gl_lds16(gB + k_,                 ldsB[buf] + ldoff);        \
    gl_lds16(gB + k_ + (size_t)16*KP, ldsB[buf] + ldoff + 512);  \
  } while (0)

  STAGE(0, ks0);
  asm volatile("s_waitcnt vmcnt(0)" ::: "memory");
  __builtin_amdgcn_s_barrier();

  int cur = 0;
  for (int ks = ks0; ks < ks1; ++ks) {
    if (ks + 1 < ks1) STAGE(cur ^ 1, ks + 1);  // prefetch overlaps compute

    bf16x8 av[8], bv[4];
    const u16* lA = ldsA[cur];
    const u16* lB = ldsB[cur];
#pragma unroll
    for (int i = 0; i < 8; ++i) av[i] = *(const bf16x8*)(lA + (wr * 128 + i * 16 + r) * 32 + kbr);
#pragma unroll
    for (int j = 0; j < 4; ++j) bv[j] = *(const bf16x8*)(lB + (wc * 64 + j * 16 + r) * 32 + kbr);

    __builtin_amdgcn_s_setprio(1);
#pragma unroll
    for (int i = 0; i < 8; ++i)
#pragma unroll
      for (int j = 0; j < 4; ++j)
        acc[i][j] = __builtin_amdgcn_mfma_f32_16x16x32_bf16(av[i], bv[j], acc[i][j], 0, 0, 0);
    __builtin_amdgcn_s_setprio(0);

    asm volatile("s_waitcnt vmcnt(0)" ::: "memory");  // next buffer landed
    __builtin_amdgcn_s_barrier();                     // all reads of cur done
    cur ^= 1;
  }
#undef STAGE

  const int col = lane & 15;
#pragma unroll
  for (int i = 0; i < 8; ++i)
#pragma unroll
    for (int j = 0; j < 4; ++j)
#pragma unroll
      for (int rr = 0; rr < 4; ++rr) {
        const int mm = m0 + wr * 128 + i * 16 + hh * 4 + rr;
        const int nn = n0 + wc * 64 + j * 16 + col;
        atomicAdd(out + (size_t)mm * NDIM + nn, acc[i][j][rr]);
      }
}

// ---------------------------------------------------------------------------
extern "C" void kernel_launch(void* const* d_in, const int* in_sizes, int n_in,
                              void* d_out, int out_size, void* d_ws, size_t ws_size,
                              hipStream_t stream) {
  const float* P = (const float*)d_in[0];   // [512][50257]
  const float* W = (const float*)d_in[1];   // [50257][1024]
  float* out = (float*)d_out;
  u64* amax = (u64*)d_ws;                               // 512 x u64 (4 KB)
  u16* A  = (u16*)((char*)d_ws + 4096);                 // [512][KP] bf16
  u16* BT = A + (size_t)MROWS * KP;                     // [1024][KP] bf16

  hipMemsetAsync(amax, 0, MROWS * sizeof(u64), stream);
  prep_fused<<<NPREP + NCONVW, 256, 0, stream>>>(P, W, out, A, BT, amax);
  gemm_kernel<<<256, 512, 0, stream>>>(A, BT, amax, out);
}